// Round 13
// baseline (319.055 us; speedup 1.0000x reference)
//
#include <hip/hip_runtime.h>
#include <hip/hip_bf16.h>

#define NPOS 784
#define WDIM 28

// ---- bf16 pack/unpack (RNE) ----
__device__ __forceinline__ unsigned int f2bf(float f) {
    union { float f; unsigned int u; } v; v.f = f;
    unsigned int r = v.u + 0x7fffu + ((v.u >> 16) & 1u);
    return r >> 16;
}
__device__ __forceinline__ float bflo(unsigned int p) {
    union { unsigned int u; float f; } v; v.u = p << 16; return v.f;
}

// ---------------- kernel 0: embedding-MLP tables (block-invariant!) ----------------
// Writes Etr/Etc fp32, transposed [m][110], to d_ws. One block.
__global__ __launch_bounds__(256) void embed_kernel(
    const float* __restrict__ rw1, const float* __restrict__ rb1,
    const float* __restrict__ rga, const float* __restrict__ rbe,
    const float* __restrict__ rw2, const float* __restrict__ rb2,
    const float* __restrict__ cw1, const float* __restrict__ cb1,
    const float* __restrict__ cga, const float* __restrict__ cbe,
    const float* __restrict__ cw2, const float* __restrict__ cb2,
    float* __restrict__ Etr, float* __restrict__ Etc)
{
    int t = threadIdx.x;
    int d = -1;
    const float *w1 = rw1, *b1 = rb1, *ga = rga, *be = rbe, *w2 = rw2, *b2 = rb2;
    float* E = Etr;
    if (t < 110) { d = t; }
    else if (t >= 128 && t < 238) { d = t - 128; w1 = cw1; b1 = cb1; ga = cga; be = cbe; w2 = cw2; b2 = cb2; E = Etc; }
    if (d < 0) return;

    float u = (d < 55) ? (-1.0f + (float)d * (2.0f / 54.0f))
                       : -(-1.0f + (float)(d - 55) * (2.0f / 54.0f));
    float hb[16], mu = 0.0f;
#pragma unroll
    for (int c = 0; c < 16; ++c) { hb[c] = u * w1[c] + b1[c]; mu += hb[c]; }
    mu *= (1.0f / 16.0f);
    float var = 0.0f;
#pragma unroll
    for (int c = 0; c < 16; ++c) { float dv = hb[c] - mu; var += dv * dv; }
    var *= (1.0f / 16.0f);
    float rstd = rsqrtf(var + 1e-5f);
#pragma unroll
    for (int c = 0; c < 16; ++c) {
        float hn = ga[c] * (hb[c] - mu) * rstd + be[c];
        hb[c] = hn / (1.0f + __expf(-hn));
    }
#pragma unroll
    for (int m = 0; m < 8; ++m) {
        float e = b2[m];
#pragma unroll
        for (int c = 0; c < 16; ++c) e += hb[c] * w2[m * 16 + c];
        E[m * 110 + d] = e;                          // transposed [m][d]
    }
}

// ---------------- kernel 1: fused 1x1-conv q/k/v + bias-init of out ----------------
__global__ __launch_bounds__(256) void qkv_kernel(
    const float* __restrict__ x,
    const float* __restrict__ wq, const float* __restrict__ bq,
    const float* __restrict__ wk, const float* __restrict__ bk,
    const float* __restrict__ wv, const float* __restrict__ bv,
    const float* __restrict__ b_out,
    float* __restrict__ Q, float* __restrict__ K, float* __restrict__ V,
    float* __restrict__ out)
{
    int idx = blockIdx.x * 256 + threadIdx.x;        // grid covers exactly 401408
    int ij = idx % NPOS;
    int oc = (idx / NPOS) & 127;
    int b  = idx / (NPOS * 128);

    float x0 = x[(b * 3 + 0) * NPOS + ij];
    float x1 = x[(b * 3 + 1) * NPOS + ij];
    float x2 = x[(b * 3 + 2) * NPOS + ij];

    float q = bq[oc] + wq[oc*3+0]*x0 + wq[oc*3+1]*x1 + wq[oc*3+2]*x2;
    float k = bk[oc] + wk[oc*3+0]*x0 + wk[oc*3+1]*x1 + wk[oc*3+2]*x2;
    float v = bv[oc] + wv[oc*3+0]*x0 + wv[oc*3+1]*x1 + wv[oc*3+2]*x2;

    int m = oc >> 3, h = oc & 7;                     // oc = m*HEADS + h
    int dst = ((b * 8 + h) * NPOS + ij) * 16 + m;
    Q[dst] = q; K[dst] = k; V[dst] = v;

    // bias-init the atomic-accumulation output (802816 elements, 2 per thread)
    for (int e = idx; e < 4 * 64 * 4 * NPOS; e += 401408) {
        int o = (e / (4 * NPOS)) & 63;
        out[e] = b_out[o];
    }
}

// ---------------- kernel 2: attention, one head per wave ----------------
// Grid = (b, ij, head-group): 6272 blocks. Wave w owns head hg*4+w alone ->
// peak live regs ~50, fits __launch_bounds__(256,6) (85-reg cap) w/o spill.
// Factorized softmax (proven r10): p_g = ec[k] * er[g] * ecol[(g+1)&3].
// Projection: per-block partial over this block's 4 heads, fp32 atomicAdd.
__global__ __launch_bounds__(256, 6) void attn_kernel(
    const float* __restrict__ Q, const float* __restrict__ K, const float* __restrict__ V,
    const float* __restrict__ Etr, const float* __restrict__ Etc,
    const float* __restrict__ w_out,
    float* __restrict__ out)
{
    __shared__ unsigned short conth[4][800];         // [wave][ (k&15)*50 + k>>4 ]: bf16 ec
    __shared__ float4         RtE[4][56];            // exp'ed rotation terms per wave
    __shared__ float          ovs[4][4][16];         // [wave(h4)][g][m]

    const int t    = threadIdx.x;
    const int wave = t >> 6, lane = t & 63;
    // XCD-aware decode: low bits round-robin (b, ij-parity) across XCDs
    const int bid = blockIdx.x;
    const int b   = (bid >> 1) & 3;
    const int r   = bid >> 3;
    const int hg  = r & 1;
    const int ij  = (r >> 1) * 2 + (bid & 1);
    const int iq  = ij / WDIM, jq = ij % WDIM;
    const int h   = hg * 4 + wave;
    const int bh  = b * 8 + h;
    const float scale = 0.57735026918962576f;        // 1/sqrt(CIN=3)

    // q in registers (wave-uniform loads, L2-hot)
    float q[16];
    {
        const float4* qp = (const float4*)(Q + (size_t)(bh * NPOS + ij) * 16);
        float4 q0 = qp[0], q1 = qp[1], q2 = qp[2], q3 = qp[3];
        q[0]=q0.x; q[1]=q0.y; q[2]=q0.z; q[3]=q0.w;
        q[4]=q1.x; q[5]=q1.y; q[6]=q1.z; q[7]=q1.w;
        q[8]=q2.x; q[9]=q2.y; q[10]=q2.z; q[11]=q2.w;
        q[12]=q3.x; q[13]=q3.y; q[14]=q3.z; q[15]=q3.w;
    }

    // rotation terms from global tables (L1/L2-hot, coalesced across lanes)
    {
        float4 mine = make_float4(-3.0e38f, -3.0e38f, -3.0e38f, -3.0e38f);
        float4 rv   = mine;
        if (lane < 55) {
            float ar = 0, ac = 0, ar5 = 0, ac5 = 0;
#pragma unroll
            for (int mm = 0; mm < 8; ++mm) {
                float ql = q[mm], qh = q[8 + mm];
                ar  += ql * Etr[mm * 110 + lane];
                ar5 += ql * Etr[mm * 110 + lane + 55];
                ac  += qh * Etc[mm * 110 + lane];
                ac5 += qh * Etc[mm * 110 + lane + 55];
            }
            rv = make_float4(ar * scale, ac * scale, ar5 * scale, ac5 * scale);
            mine = rv;
        }
#pragma unroll
        for (int off = 1; off < 64; off <<= 1) {
            mine.x = fmaxf(mine.x, __shfl_xor(mine.x, off, 64));
            mine.y = fmaxf(mine.y, __shfl_xor(mine.y, off, 64));
            mine.z = fmaxf(mine.z, __shfl_xor(mine.z, off, 64));
            mine.w = fmaxf(mine.w, __shfl_xor(mine.w, off, 64));
        }
        if (lane < 55)
            RtE[wave][lane] = make_float4(__expf(rv.x - mine.x), __expf(rv.y - mine.y),
                                          __expf(rv.z - mine.z), __expf(rv.w - mine.w));
    }

    // content pass -> bf16 strip; track max
    float maxc = -3.0e38f;
#pragma unroll 4
    for (int it = 0; it < 13; ++it) {
        int k = it * 64 + lane;
        if (k < NPOS) {
            const float4* kp = (const float4*)(K + (size_t)(bh * NPOS + k) * 16);
            float4 k0 = kp[0], k1 = kp[1], k2 = kp[2], k3 = kp[3];
            float c = q[0]*k0.x + q[1]*k0.y + q[2]*k0.z + q[3]*k0.w
                    + q[4]*k1.x + q[5]*k1.y + q[6]*k1.z + q[7]*k1.w
                    + q[8]*k2.x + q[9]*k2.y + q[10]*k2.z + q[11]*k2.w
                    + q[12]*k3.x + q[13]*k3.y + q[14]*k3.z + q[15]*k3.w;
            c *= scale;
            conth[wave][(k & 15) * 50 + (k >> 4)] = (unsigned short)f2bf(c);
            maxc = fmaxf(maxc, c);
        }
    }
#pragma unroll
    for (int off = 1; off < 64; off <<= 1) maxc = fmaxf(maxc, __shfl_xor(maxc, off, 64));

    // exp-ify the strip (same-wave RMW, in-order, no barrier)
#pragma unroll 4
    for (int it = 0; it < 13; ++it) {
        int idx = it * 64 + lane;
        if (idx < 800) {
            float cv = bflo((unsigned int)conth[wave][idx]);
            conth[wave][idx] = (unsigned short)f2bf(__expf(cv - maxc));
        }
    }

    // PV: lane = (vq = lane>>4, ch = lane&15); keys k = s*16+ch; no exp.
    {
        const int vq = lane >> 4, ch = lane & 15;
        const unsigned short* ecw = &conth[wave][ch * 50];
        const float4* RtEp = &RtE[wave][0];
        float acc[4][4];
#pragma unroll
        for (int g = 0; g < 4; ++g)
#pragma unroll
            for (int c = 0; c < 4; ++c) acc[g][c] = 0.0f;
        float ps0 = 0, ps1 = 0, ps2 = 0, ps3 = 0;
#pragma unroll 4
        for (int s = 0; s < 49; ++s) {
            int k   = s * 16 + ch;
            int row = (k * 2341) >> 16;              // k / 28 (exact for k < 784)
            int col = k - row * WDIM;
            float  ec   = bflo((unsigned int)ecw[s]);
            float4 er   = RtEp[row - iq + 27];
            float4 ecol = RtEp[col - jq + 27];
            float p0 = ec * er.x * ecol.y;
            float p1 = ec * er.y * ecol.z;
            float p2 = ec * er.z * ecol.w;
            float p3 = ec * er.w * ecol.x;
            ps0 += p0; ps1 += p1; ps2 += p2; ps3 += p3;
            float4 v = ((const float4*)(V + (size_t)(bh * NPOS + k) * 16))[vq];
            acc[0][0] += p0*v.x; acc[0][1] += p0*v.y; acc[0][2] += p0*v.z; acc[0][3] += p0*v.w;
            acc[1][0] += p1*v.x; acc[1][1] += p1*v.y; acc[1][2] += p1*v.z; acc[1][3] += p1*v.w;
            acc[2][0] += p2*v.x; acc[2][1] += p2*v.y; acc[2][2] += p2*v.z; acc[2][3] += p2*v.w;
            acc[3][0] += p3*v.x; acc[3][1] += p3*v.y; acc[3][2] += p3*v.z; acc[3][3] += p3*v.w;
        }
        // reduce over the 16 ch lanes (xor stays within each vq group)
#pragma unroll
        for (int off = 1; off < 16; off <<= 1) {
            ps0 += __shfl_xor(ps0, off, 64); ps1 += __shfl_xor(ps1, off, 64);
            ps2 += __shfl_xor(ps2, off, 64); ps3 += __shfl_xor(ps3, off, 64);
#pragma unroll
            for (int g = 0; g < 4; ++g)
#pragma unroll
                for (int c = 0; c < 4; ++c) acc[g][c] += __shfl_xor(acc[g][c], off, 64);
        }
        if (ch == 0) {
            float inv0 = 1.0f / ps0, inv1 = 1.0f / ps1, inv2 = 1.0f / ps2, inv3 = 1.0f / ps3;
#pragma unroll
            for (int c = 0; c < 4; ++c) {
                ovs[wave][0][vq * 4 + c] = acc[0][c] * inv0;
                ovs[wave][1][vq * 4 + c] = acc[1][c] * inv1;
                ovs[wave][2][vq * 4 + c] = acc[2][c] * inv2;
                ovs[wave][3][vq * 4 + c] = acc[3][c] * inv3;
            }
        }
    }
    __syncthreads();                                 // this block's 4 heads ready

    // partial output projection over 4 heads; thread = (o = t>>2, g = t&3)
    {
        int o = t >> 2, g = t & 3;
        float a = 0.0f;
#pragma unroll
        for (int m = 0; m < 16; ++m) {
            float4 w4 = *(const float4*)(w_out + o * 128 + m * 8 + hg * 4);
            a += w4.x * ovs[0][g][m] + w4.y * ovs[1][g][m]
               + w4.z * ovs[2][g][m] + w4.w * ovs[3][g][m];
        }
        atomicAdd(out + ((size_t)(b * 64 + o) * 4 + g) * NPOS + ij, a);
    }
}

extern "C" void kernel_launch(void* const* d_in, const int* in_sizes, int n_in,
                              void* d_out, int out_size, void* d_ws, size_t ws_size,
                              hipStream_t stream)
{
    const float* x     = (const float*)d_in[0];
    const float* wq    = (const float*)d_in[1];
    const float* bq    = (const float*)d_in[2];
    const float* wk    = (const float*)d_in[3];
    const float* bk    = (const float*)d_in[4];
    const float* wv    = (const float*)d_in[5];
    const float* bv    = (const float*)d_in[6];
    const float* w_out = (const float*)d_in[7];
    const float* b_out = (const float*)d_in[8];
    const float* rw1 = (const float*)d_in[9];
    const float* rb1 = (const float*)d_in[10];
    const float* rga = (const float*)d_in[11];
    const float* rbe = (const float*)d_in[12];
    const float* rw2 = (const float*)d_in[13];
    const float* rb2 = (const float*)d_in[14];
    const float* cw1 = (const float*)d_in[15];
    const float* cb1 = (const float*)d_in[16];
    const float* cga = (const float*)d_in[17];
    const float* cbe = (const float*)d_in[18];
    const float* cw2 = (const float*)d_in[19];
    const float* cb2 = (const float*)d_in[20];
    // d_in[21]/d_in[22] (ridx/cidx) unused: closed-form rotation indices.

    float* Q   = (float*)d_ws;               // 3 x 401408 floats = 4.8 MB
    float* K   = Q + 401408;
    float* V   = K + 401408;
    float* Etr = V + 401408;                 // 880 floats
    float* Etc = Etr + 880;                  // 880 floats (total 4.83 MB, proven)

    embed_kernel<<<1, 256, 0, stream>>>(rw1, rb1, rga, rbe, rw2, rb2,
                                        cw1, cb1, cga, cbe, cw2, cb2, Etr, Etc);
    qkv_kernel<<<1568, 256, 0, stream>>>(x, wq, bq, wk, bk, wv, bv, b_out,
                                         Q, K, V, (float*)d_out);
    attn_kernel<<<8 * NPOS, 256, 0, stream>>>(
        Q, K, V, Etr, Etc, w_out, (float*)d_out);
}